// Round 2
// baseline (222.916 us; speedup 1.0000x reference)
//
#include <hip/hip_runtime.h>
#include <stdint.h>

// Lightning-attention diagonal-block decayed linear attention.
// b=2, h=16, n=8192, d=e=64, BLOCK=64 -> 4096 independent 64x64x64 GEMM pairs.
// Memory-bound target: ~168-268 MB HBM traffic -> 27-43 us floor.
// Strategy: 1024 blocks x 4 tiles each, register-prefetch pipeline to keep
// HBM loads in flight across compute; single barrier pair per tile; S' strip
// overlaid on the wave's own dead Q strip (27.6 KB LDS, no extra barrier
// needed: same-wave LDS ops are ordered).

#define H_   16
#define N_   8192
#define G_   (N_ / 64)
#define LDSP 72   // padded LDS row stride in bf16 elems
#define TPB  4    // tiles per block

typedef __attribute__((ext_vector_type(8))) short bf16x8;
typedef __attribute__((ext_vector_type(4))) float f32x4;

union F4 { float4 v; float f[4]; };

static __device__ __forceinline__ unsigned short f2bf(float x) {
    union { float f; uint32_t u; } un; un.f = x;
    uint32_t u = un.u;
    u += 0x7FFFu + ((u >> 16) & 1u);   // round-to-nearest-even
    return (unsigned short)(u >> 16);
}

static __device__ __forceinline__ ushort4 cvt4(float4 a) {
    return make_ushort4(f2bf(a.x), f2bf(a.y), f2bf(a.z), f2bf(a.w));
}

__global__ __launch_bounds__(256, 4)
void lightning_diag(const float* __restrict__ q,
                    const float* __restrict__ k,
                    const float* __restrict__ v,
                    const float* __restrict__ s,
                    float* __restrict__ out)
{
    __shared__ unsigned short Qs[64 * LDSP];  // Q strip; reused per-wave as S'
    __shared__ unsigned short Ks[64 * LDSP];
    __shared__ unsigned short Vt[64 * LDSP];  // V transposed: [e][j]

    const int tid  = threadIdx.x;
    const int wave = tid >> 6;
    const int lane = tid & 63;
    const int g16  = lane >> 4;
    const int l16  = lane & 15;
    const int rq   = tid >> 4;   // V 4x4-block row-quad 0..15
    const int cq   = tid & 15;   // V 4x4-block col-quad 0..15

    const int    t0    = blockIdx.x * TPB;       // first tile of this block
    const int    hi    = (t0 / G_) % H_;         // same head for all TPB tiles
    const size_t base0 = (size_t)t0 * 4096;

    const float c = -s[hi] * 1.44269504088896f;  // -s * log2(e)

    // ---- prologue: load tile 0 into registers ----
    F4 pq[4], pk[4], pv[4];
    {
        const float4* qg = (const float4*)(q + base0);
        const float4* kg = (const float4*)(k + base0);
        const float4* vg = (const float4*)(v + base0);
        #pragma unroll
        for (int it = 0; it < 4; ++it) {
            const int fi = tid + it * 256;
            pq[it].v = qg[fi];
            pk[it].v = kg[fi];
            pv[it].v = vg[(4 * rq + it) * 16 + cq];
        }
    }

    #pragma unroll
    for (int t = 0; t < TPB; ++t) {
        const size_t base = base0 + (size_t)t * 4096;

        // ---- stage tile t registers -> LDS (bf16) ----
        #pragma unroll
        for (int it = 0; it < 4; ++it) {
            const int fi  = tid + it * 256;
            const int row = fi >> 4;
            const int col = (fi & 15) << 2;
            *(ushort4*)&Qs[row * LDSP + col] = cvt4(pq[it].v);
            *(ushort4*)&Ks[row * LDSP + col] = cvt4(pk[it].v);
        }
        // V: 4x4 in-register transpose, ushort4 writes along j
        #pragma unroll
        for (int j = 0; j < 4; ++j) {
            ushort4 w = make_ushort4(f2bf(pv[0].f[j]), f2bf(pv[1].f[j]),
                                     f2bf(pv[2].f[j]), f2bf(pv[3].f[j]));
            *(ushort4*)&Vt[(4 * cq + j) * LDSP + 4 * rq] = w;
        }

        // ---- issue tile t+1 loads (latency hidden under barrier+compute) ----
        if (t + 1 < TPB) {
            const size_t nb = base + 4096;
            const float4* qn = (const float4*)(q + nb);
            const float4* kn = (const float4*)(k + nb);
            const float4* vn = (const float4*)(v + nb);
            #pragma unroll
            for (int it = 0; it < 4; ++it) {
                const int fi = tid + it * 256;
                pq[it].v = qn[fi];
                pk[it].v = kn[fi];
                pv[it].v = vn[(4 * rq + it) * 16 + cq];
            }
        }

        __syncthreads();

        // ---- GEMM1: S strip (16x64) = Q[wave strip] * K^T ----
        f32x4 acc[4];
        #pragma unroll
        for (int tt = 0; tt < 4; ++tt) acc[tt] = (f32x4){0.f, 0.f, 0.f, 0.f};

        const int arow = wave * 16 + l16;
        const bf16x8 a0 = *(const bf16x8*)&Qs[arow * LDSP + g16 * 8];
        const bf16x8 a1 = *(const bf16x8*)&Qs[arow * LDSP + g16 * 8 + 32];
        #pragma unroll
        for (int tc = 0; tc < 4; ++tc) {
            const int brow = tc * 16 + l16;
            const bf16x8 b0 = *(const bf16x8*)&Ks[brow * LDSP + g16 * 8];
            const bf16x8 b1 = *(const bf16x8*)&Ks[brow * LDSP + g16 * 8 + 32];
            acc[tc] = __builtin_amdgcn_mfma_f32_16x16x32_bf16(a0, b0, acc[tc], 0, 0, 0);
            acc[tc] = __builtin_amdgcn_mfma_f32_16x16x32_bf16(a1, b1, acc[tc], 0, 0, 0);
        }

        // ---- decay * causal mask, write S' into own (dead) Q strip ----
        // C/D layout: col = lane&15, row = 4*(lane>>4)+reg.  No barrier needed:
        // the strip is written and read by this wave only (same-wave DS order).
        unsigned short* ss = &Qs[wave * 16 * LDSP];
        #pragma unroll
        for (int tc = 0; tc < 4; ++tc) {
            #pragma unroll
            for (int r = 0; r < 4; ++r) {
                const int il   = wave * 16 + g16 * 4 + r;
                const int jl   = tc * 16 + l16;
                const int diff = il - jl;
                const float f  = (diff >= 0)
                               ? __builtin_amdgcn_exp2f(c * (float)diff) : 0.0f;
                ss[(g16 * 4 + r) * LDSP + jl] = f2bf(acc[tc][r] * f);
            }
        }

        // ---- GEMM2: O strip (16x64) = S' * V ----
        f32x4 oacc[4];
        #pragma unroll
        for (int tt = 0; tt < 4; ++tt) oacc[tt] = (f32x4){0.f, 0.f, 0.f, 0.f};
        const bf16x8 sa0 = *(const bf16x8*)&ss[l16 * LDSP + g16 * 8];
        const bf16x8 sa1 = *(const bf16x8*)&ss[l16 * LDSP + g16 * 8 + 32];
        #pragma unroll
        for (int nc = 0; nc < 4; ++nc) {
            const int vrow = nc * 16 + l16;
            const bf16x8 b0 = *(const bf16x8*)&Vt[vrow * LDSP + g16 * 8];
            const bf16x8 b1 = *(const bf16x8*)&Vt[vrow * LDSP + g16 * 8 + 32];
            oacc[nc] = __builtin_amdgcn_mfma_f32_16x16x32_bf16(sa0, b0, oacc[nc], 0, 0, 0);
            oacc[nc] = __builtin_amdgcn_mfma_f32_16x16x32_bf16(sa1, b1, oacc[nc], 0, 0, 0);
        }

        // ---- store O (fp32), 16-lane 64B contiguous runs ----
        float* og = out + base;
        #pragma unroll
        for (int nc = 0; nc < 4; ++nc) {
            #pragma unroll
            for (int r = 0; r < 4; ++r) {
                og[(wave * 16 + g16 * 4 + r) * 64 + nc * 16 + l16] = oacc[nc][r];
            }
        }

        if (t + 1 < TPB) __syncthreads();   // LDS write-after-read for next tile
    }
}

extern "C" void kernel_launch(void* const* d_in, const int* in_sizes, int n_in,
                              void* d_out, int out_size, void* d_ws, size_t ws_size,
                              hipStream_t stream) {
    const float* q = (const float*)d_in[0];
    const float* k = (const float*)d_in[1];
    const float* v = (const float*)d_in[2];
    const float* s = (const float*)d_in[3];
    float* out = (float*)d_out;
    const int tiles = in_sizes[0] / 4096;   // b*h*G = 4096
    lightning_diag<<<tiles / TPB, 256, 0, stream>>>(q, k, v, s, out);
}